// Round 1
// baseline (621.801 us; speedup 1.0000x reference)
//
#include <hip/hip_runtime.h>
#include <hip/hip_bf16.h>
#include <stdint.h>

#define DD 32   // input dim
#define HH 64   // hidden dim

typedef float f32x4 __attribute__((ext_vector_type(4)));
typedef short s16x8 __attribute__((ext_vector_type(8)));

__device__ __forceinline__ float fexp(float x) {
  return __builtin_amdgcn_exp2f(x * 1.44269504088896340736f);
}
__device__ __forceinline__ float fsig(float x) {
  return __builtin_amdgcn_rcpf(1.0f + fexp(-x));
}
__device__ __forceinline__ float ftanh(float x) {
  // 1 - 2/(1+exp(2x)); saturates correctly at +-inf
  return 1.0f - 2.0f * __builtin_amdgcn_rcpf(1.0f + fexp(2.0f * x));
}
__device__ __forceinline__ uint32_t f2bf1(float f) {
  union { float f; uint32_t u; } v; v.f = f;
  return (v.u + 0x7FFFu + ((v.u >> 16) & 1u)) >> 16;  // RNE
}
__device__ __forceinline__ uint32_t f2bf2(float lo, float hi) {
  return f2bf1(lo) | (f2bf1(hi) << 16);
}

__global__ __launch_bounds__(256, 1)
void lstm_fused(const float* __restrict__ x,
                const float* __restrict__ W_ih,
                const float* __restrict__ W_hh,
                const float* __restrict__ b_ih,
                const float* __restrict__ b_hh,
                const float* __restrict__ fc_W,
                const float* __restrict__ fc_b,
                float* __restrict__ out,
                int T)
{
  const int tid  = threadIdx.x;
  const int wv   = tid >> 6;     // wave 0..3
  const int lane = tid & 63;
  const int lr   = lane & 15;    // A-row (batch) / D-col (n) index
  const int lq   = lane >> 4;    // k-group 0..3
  const int bm   = blockIdx.x * 16;

  __shared__ __align__(16) uint16_t hbuf[2][16 * 64]; // bf16 h, double buffered, XOR-swizzled
  __shared__ __align__(16) float    hf[16 * 64];      // final h fp32 for FC

  // ---- preload weights as persistent B fragments (bf16 in VGPRs) ----
  // wave wv owns n-tiles {64*j + 16*wv : j=0..3}; lane's column h0:
  const int h0 = 16 * wv + lr;
  s16x8 Bx[4];        // input-proj weights, K=32 (one k-tile)
  s16x8 Bh[2][4];     // recurrent weights, K=64 (two k-tiles)
  float bias[4];
  #pragma unroll
  for (int j = 0; j < 4; ++j) {
    const int n = 64 * j + h0;
    {
      const float* p = W_ih + n * DD + lq * 8;
      f32x4 a = *(const f32x4*)p;
      f32x4 b = *(const f32x4*)(p + 4);
      union { uint32_t u[4]; s16x8 s; } pk;
      pk.u[0] = f2bf2(a[0], a[1]); pk.u[1] = f2bf2(a[2], a[3]);
      pk.u[2] = f2bf2(b[0], b[1]); pk.u[3] = f2bf2(b[2], b[3]);
      Bx[j] = pk.s;
    }
    #pragma unroll
    for (int kt = 0; kt < 2; ++kt) {
      const float* p = W_hh + n * HH + kt * 32 + lq * 8;
      f32x4 a = *(const f32x4*)p;
      f32x4 b = *(const f32x4*)(p + 4);
      union { uint32_t u[4]; s16x8 s; } pk;
      pk.u[0] = f2bf2(a[0], a[1]); pk.u[1] = f2bf2(a[2], a[3]);
      pk.u[2] = f2bf2(b[0], b[1]); pk.u[3] = f2bf2(b[2], b[3]);
      Bh[kt][j] = pk.s;
    }
    bias[j] = b_ih[n] + b_hh[n];
  }

  // zero h buffer 0 (bf16 zero == 0x0000)
  for (int i = tid; i < 16 * 64; i += 256) hbuf[0][i] = 0;

  float c[4]  = {0.f, 0.f, 0.f, 0.f};
  float hn[4] = {0.f, 0.f, 0.f, 0.f};

  // per-lane x source: batch row (bm+lr), k-offset lq*8; prefetch t=0
  const float* xbase = x + (size_t)(bm + lr) * (size_t)T * DD + lq * 8;
  f32x4 xa = *(const f32x4*)xbase;
  f32x4 xb = *(const f32x4*)(xbase + 4);

  __syncthreads();

  const f32x4 zz = {0.f, 0.f, 0.f, 0.f};
  const int sw = lr & 7;

  auto step = [&](int t, const uint16_t* __restrict__ hr, uint16_t* __restrict__ hw) {
    // convert current x regs to A fragment
    union { uint32_t u[4]; s16x8 s; } ax;
    ax.u[0] = f2bf2(xa[0], xa[1]); ax.u[1] = f2bf2(xa[2], xa[3]);
    ax.u[2] = f2bf2(xb[0], xb[1]); ax.u[3] = f2bf2(xb[2], xb[3]);
    // prefetch next timestep's x (no h dependence — overlaps everything below)
    {
      const size_t off = (size_t)((t + 1 < T) ? (t + 1) : t) * DD;
      xa = *(const f32x4*)(xbase + off);
      xb = *(const f32x4*)(xbase + off + 4);
    }
    // x-part MFMAs (before barrier: overlaps other waves finishing prev step)
    f32x4 acc[4];
    #pragma unroll
    for (int j = 0; j < 4; ++j)
      acc[j] = __builtin_amdgcn_mfma_f32_16x16x32_bf16(ax.s, Bx[j], zz, 0, 0, 0);

    __syncthreads();  // h_t writes (prev iter) now visible

    // read A_h fragments from swizzled LDS: row lr, chunks lq and lq+4
    s16x8 ah0 = *(const s16x8*)(hr + lr * 64 + (((lq    ) ^ sw) << 3));
    s16x8 ah1 = *(const s16x8*)(hr + lr * 64 + (((lq + 4) ^ sw) << 3));
    #pragma unroll
    for (int j = 0; j < 4; ++j)
      acc[j] = __builtin_amdgcn_mfma_f32_16x16x32_bf16(ah0, Bh[0][j], acc[j], 0, 0, 0);
    #pragma unroll
    for (int j = 0; j < 4; ++j)
      acc[j] = __builtin_amdgcn_mfma_f32_16x16x32_bf16(ah1, Bh[1][j], acc[j], 0, 0, 0);

    // elementwise LSTM cell update; lane owns cells (m = 4*lq+r, h0)
    #pragma unroll
    for (int r = 0; r < 4; ++r) {
      float gi = acc[0][r] + bias[0];
      float gf = acc[1][r] + bias[1];
      float gg = acc[2][r] + bias[2];
      float go = acc[3][r] + bias[3];
      float ig = fsig(gi);
      float fg = fsig(gf);
      float gt = ftanh(gg);
      float og = fsig(go);
      c[r] = fg * c[r] + ig * gt;
      float hv = og * ftanh(c[r]);
      hn[r] = hv;
      const int m = 4 * lq + r;
      // swizzled store: elem index m*64 + ((col>>3)^(m&7))*8 + (col&7)
      hw[m * 64 + ((((h0 >> 3) ^ (m & 7))) << 3) + (h0 & 7)] = (uint16_t)f2bf1(hv);
    }
    // no barrier here: next step's pre-barrier work doesn't touch hw's buffer;
    // the next step's __syncthreads orders these writes before its reads
  };

  for (int t = 0; t < T; t += 2) {
    step(t,     hbuf[0], hbuf[1]);
    step(t + 1, hbuf[1], hbuf[0]);
  }

  // ---- epilogue: logits = h_last @ fc_W^T + fc_b (fp32) ----
  #pragma unroll
  for (int r = 0; r < 4; ++r)
    hf[(4 * lq + r) * 64 + h0] = hn[r];
  __syncthreads();
  if (tid < 160) {
    const int m = tid / 10, cl = tid % 10;
    float s = fc_b[cl];
    const float* wr = fc_W + cl * HH;
    const float* hm = hf + m * 64;
    #pragma unroll
    for (int k = 0; k < HH; ++k) s += hm[k] * wr[k];
    out[(size_t)(bm + m) * 10 + cl] = s;
  }
}

extern "C" void kernel_launch(void* const* d_in, const int* in_sizes, int n_in,
                              void* d_out, int out_size, void* d_ws, size_t ws_size,
                              hipStream_t stream) {
  const float* x    = (const float*)d_in[0];
  const float* W_ih = (const float*)d_in[1];
  const float* W_hh = (const float*)d_in[2];
  const float* b_ih = (const float*)d_in[3];
  const float* b_hh = (const float*)d_in[4];
  const float* fc_W = (const float*)d_in[5];
  const float* fc_b = (const float*)d_in[6];
  float* out = (float*)d_out;

  const int B = out_size / 10;            // 2048
  const int T = in_sizes[0] / (B * DD);   // 1024

  dim3 grid(B / 16), block(256);
  hipLaunchKernelGGL(lstm_fused, grid, block, 0, stream,
                     x, W_ih, W_hh, b_ih, b_hh, fc_W, fc_b, out, T);
}